// Round 10
// baseline (893.649 us; speedup 1.0000x reference)
//
#include <hip/hip_runtime.h>
#include <math.h>

#define N_NODES 50000
#define N_EDGES 800000
#define F_INPUT 128
#define HID 64
#define NHEAD 3
#define NGRAPH 50
#define D1 192   // NHEAD*HID
#define D2 384   // 2*D1 (fs|fd)

// 16-lane (DPP row) all-reduce add via row_ror rotate-add; pure VALU, no DS pipe.
#define ROR_ADD(v, C) \
  ((v) + __int_as_float(__builtin_amdgcn_update_dpp(0, __float_as_int(v), (C), 0xF, 0xF, true)))

// ---------------- graph-structure kernels (run once per call) ----------------

__global__ void zero_int_kernel(int* __restrict__ p, int n) {
  int i = blockIdx.x * blockDim.x + threadIdx.x;
  if (i < n) p[i] = 0;
}

__global__ void hist_kernel(const int* __restrict__ dst, int* __restrict__ counts, int e) {
  int i = blockIdx.x * blockDim.x + threadIdx.x;
  if (i < e) atomicAdd(&counts[dst[i]], 1);
}

__global__ __launch_bounds__(256)
void scan_blocks_kernel(const int* __restrict__ counts, int* __restrict__ indptr,
                        int* __restrict__ bsum, int n) {
  __shared__ int wt[4];
  int tid = threadIdx.x, lane = tid & 63, wid = tid >> 6;
  int i = blockIdx.x * 256 + tid;
  int x = (i < n) ? counts[i] : 0;
  #pragma unroll
  for (int off = 1; off < 64; off <<= 1) {
    int t = __shfl_up(x, off, 64);
    if (lane >= off) x += t;
  }
  if (lane == 63) wt[wid] = x;
  __syncthreads();
  int woff = 0;
  #pragma unroll
  for (int w = 0; w < 4; ++w) if (w < wid) woff += wt[w];
  x += woff;
  if (i < n) indptr[i + 1] = x;
  if (tid == 255) bsum[blockIdx.x] = x;
}

__global__ __launch_bounds__(256)
void scan_sums_kernel(int* __restrict__ bsum, int nb) {  // nb <= 256
  __shared__ int wt[4];
  int tid = threadIdx.x, lane = tid & 63, wid = tid >> 6;
  int v = (tid < nb) ? bsum[tid] : 0;
  int x = v;
  #pragma unroll
  for (int off = 1; off < 64; off <<= 1) {
    int t = __shfl_up(x, off, 64);
    if (lane >= off) x += t;
  }
  if (lane == 63) wt[wid] = x;
  __syncthreads();
  int woff = 0;
  #pragma unroll
  for (int w = 0; w < 4; ++w) if (w < wid) woff += wt[w];
  if (tid < nb) bsum[tid] = woff + x - v;  // exclusive
}

__global__ void add_offs_kernel(int* __restrict__ indptr, const int* __restrict__ bsum,
                                int* __restrict__ cursor, int n) {
  int i = blockIdx.x * 256 + threadIdx.x;
  if (i == 0) { indptr[0] = 0; cursor[0] = 0; }
  if (i < n) {
    int v = indptr[i + 1] + bsum[blockIdx.x];
    indptr[i + 1] = v;
    if (i + 1 < n) cursor[i + 1] = v;
  }
}

__global__ void scatter_kernel(const int* __restrict__ src, const int* __restrict__ dst,
                               int* __restrict__ cursor, int* __restrict__ ssrc, int e) {
  int i = blockIdx.x * blockDim.x + threadIdx.x;
  if (i < e) {
    int pos = atomicAdd(&cursor[dst[i]], 1);
    ssrc[pos] = src[i];
  }
}

// ---------------- fused src/dst feature GEMM: C[M,384] = A[M,K] @ [Wsrc|Wdst] + bias
// 128x128 tile, BK=32, 256 threads, 8x8 microtile (4+4 split at offset 64),
// As transposed [k][m] (conflict-free), reg prefetch, 4 blocks/CU.
// Grid: x = col-block (3), y = row-block -> 3 blocks sharing an A-tile dispatch together.

__global__ __launch_bounds__(256, 4)
void gemm_kernel(const float* __restrict__ A, int M, int K,
                 const float* __restrict__ Wsrc, const float* __restrict__ bsrc,
                 const float* __restrict__ Wdst, const float* __restrict__ bdst,
                 float* __restrict__ C) {
  __shared__ float As[32][132];   // [k][m]
  __shared__ float Bs[32][132];   // [k][n]
  const int tid = threadIdx.x;
  const int tx = tid & 15;        // n-group
  const int ty = tid >> 4;        // m-group
  const int m0 = blockIdx.y * 128;
  const int n0 = blockIdx.x * 128;

  float4 pa[4], pb[4];

#define LOAD_A(k0)                                                        \
  {                                                                       \
    _Pragma("unroll")                                                     \
    for (int p = 0; p < 4; ++p) {                                         \
      int fidx = tid + p * 256;                                           \
      int m = fidx & 127, kq = fidx >> 7;                                 \
      int gm = m0 + m;                                                    \
      pa[p] = make_float4(0.f, 0.f, 0.f, 0.f);                            \
      if (gm < M) pa[p] = *(const float4*)(A + (size_t)gm * K + (k0) + kq * 4); \
    }                                                                     \
  }
#define LOAD_B(k0)                                                        \
  {                                                                       \
    _Pragma("unroll")                                                     \
    for (int p = 0; p < 4; ++p) {                                         \
      int fidx = tid + p * 256;                                           \
      int kr = fidx >> 5, c4 = fidx & 31;                                 \
      int col = n0 + c4 * 4;                                              \
      const float* wp = (col < D1)                                        \
          ? (Wsrc + (size_t)((k0) + kr) * D1 + col)                       \
          : (Wdst + (size_t)((k0) + kr) * D1 + col - D1);                 \
      pb[p] = *(const float4*)wp;                                         \
    }                                                                     \
  }
#define STORE_AB()                                                        \
  {                                                                       \
    _Pragma("unroll")                                                     \
    for (int p = 0; p < 4; ++p) {                                         \
      int fidx = tid + p * 256;                                           \
      int m = fidx & 127, kq = fidx >> 7;                                 \
      As[kq * 4 + 0][m] = pa[p].x;                                        \
      As[kq * 4 + 1][m] = pa[p].y;                                        \
      As[kq * 4 + 2][m] = pa[p].z;                                        \
      As[kq * 4 + 3][m] = pa[p].w;                                        \
      int kr = fidx >> 5, c4 = fidx & 31;                                 \
      *(float4*)&Bs[kr][c4 * 4] = pb[p];                                  \
    }                                                                     \
  }

  LOAD_A(0); LOAD_B(0);
  STORE_AB();
  __syncthreads();

  float acc[8][8] = {};
  const int KT = K >> 5;   // 4 or 6
  for (int kt = 0; kt < KT; ++kt) {
    if (kt + 1 < KT) { LOAD_A((kt + 1) * 32); LOAD_B((kt + 1) * 32); }
    #pragma unroll 8
    for (int k = 0; k < 32; ++k) {
      float4 a0 = *(const float4*)&As[k][ty * 4];
      float4 a1 = *(const float4*)&As[k][ty * 4 + 64];
      float4 b0 = *(const float4*)&Bs[k][tx * 4];
      float4 b1 = *(const float4*)&Bs[k][tx * 4 + 64];
      float aa[8] = {a0.x, a0.y, a0.z, a0.w, a1.x, a1.y, a1.z, a1.w};
      float bb[8] = {b0.x, b0.y, b0.z, b0.w, b1.x, b1.y, b1.z, b1.w};
      #pragma unroll
      for (int i = 0; i < 8; ++i)
        #pragma unroll
        for (int j = 0; j < 8; ++j)
          acc[i][j] = fmaf(aa[i], bb[j], acc[i][j]);
    }
    __syncthreads();
    if (kt + 1 < KT) {
      STORE_AB();
      __syncthreads();
    }
  }

  // bias (192 boundary is float4-aligned, no straddle)
  float bb[8];
  {
    int c0 = n0 + tx * 4;
    const float* bp0 = (c0 < D1) ? (bsrc + c0) : (bdst + c0 - D1);
    int c1 = n0 + tx * 4 + 64;
    const float* bp1 = (c1 < D1) ? (bsrc + c1) : (bdst + c1 - D1);
    float4 v0 = *(const float4*)bp0;
    float4 v1 = *(const float4*)bp1;
    bb[0] = v0.x; bb[1] = v0.y; bb[2] = v0.z; bb[3] = v0.w;
    bb[4] = v1.x; bb[5] = v1.y; bb[6] = v1.z; bb[7] = v1.w;
  }
  #pragma unroll
  for (int i = 0; i < 8; ++i) {
    int r = m0 + ty * 4 + ((i < 4) ? i : 64 + i - 4);
    if (r < M) {
      float4 o0, o1;
      o0.x = acc[i][0] + bb[0]; o0.y = acc[i][1] + bb[1];
      o0.z = acc[i][2] + bb[2]; o0.w = acc[i][3] + bb[3];
      o1.x = acc[i][4] + bb[4]; o1.y = acc[i][5] + bb[5];
      o1.z = acc[i][6] + bb[6]; o1.w = acc[i][7] + bb[7];
      *(float4*)(C + (size_t)r * D2 + n0 + tx * 4) = o0;
      *(float4*)(C + (size_t)r * D2 + n0 + tx * 4 + 64) = o1;
    }
  }
}

// ---------------- edge phase: 1 node/wave, 4 groups x 16 lanes, lane owns 12 dims ----
// 2-deep feature prefetch (f <- g1 <- g2), ssrc fetched 3 iterations ahead.

template <int LAST>
__global__ __launch_bounds__(256)
void edge_kernel(const float* __restrict__ fsfd, const int* __restrict__ indptr,
                 const int* __restrict__ ssrc, const float* __restrict__ attn,
                 float* __restrict__ out) {
  int wave = (blockIdx.x * blockDim.x + threadIdx.x) >> 6;
  if (wave >= N_NODES) return;
  int lane = threadIdx.x & 63;
  int grp = lane >> 4;            // group = which edge of the 4-batch
  int l16 = lane & 15;            // dim-group within edge
  int db = l16 * 4;               // dim base in each head
  const int node = wave;
  const float LOG2E = 1.4426950408889634f;

  float fd[12], a[12];
  {
    const float* fdp = fsfd + (size_t)node * D2 + D1;
    *(float4*)&fd[0] = *(const float4*)(fdp + db);
    *(float4*)&fd[4] = *(const float4*)(fdp + 64 + db);
    *(float4*)&fd[8] = *(const float4*)(fdp + 128 + db);
    float4 a0 = *(const float4*)(attn + db);
    float4 a1 = *(const float4*)(attn + 64 + db);
    float4 a2 = *(const float4*)(attn + 128 + db);
    a[0]=a0.x*LOG2E; a[1]=a0.y*LOG2E; a[2]=a0.z*LOG2E; a[3]=a0.w*LOG2E;
    a[4]=a1.x*LOG2E; a[5]=a1.y*LOG2E; a[6]=a1.z*LOG2E; a[7]=a1.w*LOG2E;
    a[8]=a2.x*LOG2E; a[9]=a2.y*LOG2E; a[10]=a2.z*LOG2E; a[11]=a2.w*LOG2E;
  }
  int beg = indptr[node], end = indptr[node + 1];
  int deg = end - beg;
  int nit = (deg + 3) >> 2;

  float m[3] = {-INFINITY, -INFINITY, -INFINITY};
  float d[3] = {0.f, 0.f, 0.f};
  float c[12] = {0,0,0,0,0,0,0,0,0,0,0,0};
  float f[12]  = {0,0,0,0,0,0,0,0,0,0,0,0};
  float g1[12] = {0,0,0,0,0,0,0,0,0,0,0,0};
  float g2[12] = {0,0,0,0,0,0,0,0,0,0,0,0};

  int e0 = beg + grp;
  // prologue: load iter-0 and iter-1 features; fetch iter-2 src
  if (e0 < end) {
    int s = ssrc[e0];
    const float* p = fsfd + (size_t)s * D2;
    *(float4*)&f[0] = *(const float4*)(p + db);
    *(float4*)&f[4] = *(const float4*)(p + 64 + db);
    *(float4*)&f[8] = *(const float4*)(p + 128 + db);
  }
  if (e0 + 4 < end) {
    int s = ssrc[e0 + 4];
    const float* p = fsfd + (size_t)s * D2;
    *(float4*)&g1[0] = *(const float4*)(p + db);
    *(float4*)&g1[4] = *(const float4*)(p + 64 + db);
    *(float4*)&g1[8] = *(const float4*)(p + 128 + db);
  }
  int s2 = 0;
  { int e2 = e0 + 8; if (e2 < end) s2 = ssrc[e2]; }

  for (int it = 0; it < nit; ++it) {
    int eC = e0 + it * 4;
    // prefetch features for it+2 (src fetched 2 iters ago), src for it+3
    if (eC + 8 < end) {
      const float* p = fsfd + (size_t)s2 * D2;
      *(float4*)&g2[0] = *(const float4*)(p + db);
      *(float4*)&g2[4] = *(const float4*)(p + 64 + db);
      *(float4*)&g2[8] = *(const float4*)(p + 128 + db);
    }
    int s3 = 0;
    { int e3 = eC + 12; if (e3 < end) s3 = ssrc[e3]; }

    float ph0 = 0.f, ph1 = 0.f, ph2 = 0.f;
    #pragma unroll
    for (int i = 0; i < 4; ++i) {
      float t = f[i] + fd[i]; t = fmaxf(t, 0.2f * t); ph0 = fmaf(t, a[i], ph0);
    }
    #pragma unroll
    for (int i = 4; i < 8; ++i) {
      float t = f[i] + fd[i]; t = fmaxf(t, 0.2f * t); ph1 = fmaf(t, a[i], ph1);
    }
    #pragma unroll
    for (int i = 8; i < 12; ++i) {
      float t = f[i] + fd[i]; t = fmaxf(t, 0.2f * t); ph2 = fmaf(t, a[i], ph2);
    }
    // 16-lane allreduce via DPP row_ror rotate-adds (no DS pipe)
    ph0 = ROR_ADD(ph0, 0x128); ph1 = ROR_ADD(ph1, 0x128); ph2 = ROR_ADD(ph2, 0x128);
    ph0 = ROR_ADD(ph0, 0x124); ph1 = ROR_ADD(ph1, 0x124); ph2 = ROR_ADD(ph2, 0x124);
    ph0 = ROR_ADD(ph0, 0x122); ph1 = ROR_ADD(ph1, 0x122); ph2 = ROR_ADD(ph2, 0x122);
    ph0 = ROR_ADD(ph0, 0x121); ph1 = ROR_ADD(ph1, 0x121); ph2 = ROR_ADD(ph2, 0x121);
    if (eC < end) {
      {
        float nm = fmaxf(m[0], ph0);
        float ex = exp2f(-fabsf(ph0 - m[0]));
        float sc = (ph0 > m[0]) ? ex : 1.f;
        float p  = (ph0 > m[0]) ? 1.f : ex;
        d[0] = d[0] * sc + p; m[0] = nm;
        #pragma unroll
        for (int j = 0; j < 4; ++j) c[j] = fmaf(p, f[j], c[j] * sc);
      }
      {
        float nm = fmaxf(m[1], ph1);
        float ex = exp2f(-fabsf(ph1 - m[1]));
        float sc = (ph1 > m[1]) ? ex : 1.f;
        float p  = (ph1 > m[1]) ? 1.f : ex;
        d[1] = d[1] * sc + p; m[1] = nm;
        #pragma unroll
        for (int j = 0; j < 4; ++j) c[4 + j] = fmaf(p, f[4 + j], c[4 + j] * sc);
      }
      {
        float nm = fmaxf(m[2], ph2);
        float ex = exp2f(-fabsf(ph2 - m[2]));
        float sc = (ph2 > m[2]) ? ex : 1.f;
        float p  = (ph2 > m[2]) ? 1.f : ex;
        d[2] = d[2] * sc + p; m[2] = nm;
        #pragma unroll
        for (int j = 0; j < 4; ++j) c[8 + j] = fmaf(p, f[8 + j], c[8 + j] * sc);
      }
    }
    #pragma unroll
    for (int i = 0; i < 12; ++i) { f[i] = g1[i]; g1[i] = g2[i]; }
    s2 = s3;
  }

  // merge the 4 per-group partial softmaxes (cross-group: offsets 16, 32)
  float M0 = m[0], M1 = m[1], M2 = m[2];
  #pragma unroll
  for (int off = 16; off < 64; off <<= 1) {
    M0 = fmaxf(M0, __shfl_xor(M0, off, 64));
    M1 = fmaxf(M1, __shfl_xor(M1, off, 64));
    M2 = fmaxf(M2, __shfl_xor(M2, off, 64));
  }
  float s0 = (m[0] == M0) ? 1.f : exp2f(m[0] - M0);
  float s1 = (m[1] == M1) ? 1.f : exp2f(m[1] - M1);
  float s2f = (m[2] == M2) ? 1.f : exp2f(m[2] - M2);
  d[0] *= s0; d[1] *= s1; d[2] *= s2f;
  #pragma unroll
  for (int j = 0; j < 4; ++j) { c[j] *= s0; c[4 + j] *= s1; c[8 + j] *= s2f; }
  #pragma unroll
  for (int off = 16; off < 64; off <<= 1) {
    d[0] += __shfl_xor(d[0], off, 64);
    d[1] += __shfl_xor(d[1], off, 64);
    d[2] += __shfl_xor(d[2], off, 64);
    #pragma unroll
    for (int i = 0; i < 12; ++i) c[i] += __shfl_xor(c[i], off, 64);
  }
  float r[12];
  float i0 = d[0] > 0.f ? 1.f / d[0] : 0.f;
  float i1 = d[1] > 0.f ? 1.f / d[1] : 0.f;
  float i2 = d[2] > 0.f ? 1.f / d[2] : 0.f;
  #pragma unroll
  for (int j = 0; j < 4; ++j) { r[j] = c[j] * i0; r[4 + j] = c[4 + j] * i1; r[8 + j] = c[8 + j] * i2; }

  if (grp == 0) {
    if (LAST) {
      float4 o;
      o.x = (r[0] + r[4] + r[8])  * (1.f / 3.f);
      o.y = (r[1] + r[5] + r[9])  * (1.f / 3.f);
      o.z = (r[2] + r[6] + r[10]) * (1.f / 3.f);
      o.w = (r[3] + r[7] + r[11]) * (1.f / 3.f);
      *(float4*)(out + (size_t)node * HID + db) = o;
    } else {
      float* op = out + (size_t)node * D1;
      *(float4*)(op + db)       = *(float4*)&r[0];
      *(float4*)(op + 64 + db)  = *(float4*)&r[4];
      *(float4*)(op + 128 + db) = *(float4*)&r[8];
    }
  }
}

// ---------------- per-graph mean pool + 3-layer MLP ----------------

__global__ __launch_bounds__(256)
void pool_mlp_kernel(const float* __restrict__ h, const int* __restrict__ gids,
                     const float* __restrict__ W1, const float* __restrict__ b1,
                     const float* __restrict__ W2, const float* __restrict__ b2,
                     const float* __restrict__ W3, const float* __restrict__ b3,
                     float* __restrict__ out) {
  int g = blockIdx.x;
  int tid = threadIdx.x;
  int lane = tid & 63, wid = tid >> 6;
  int lo, hi;
  { int l = 0, r = N_NODES; while (l < r) { int mid = (l + r) >> 1; if (gids[mid] < g) l = mid + 1; else r = mid; } lo = l; }
  { int l = 0, r = N_NODES; while (l < r) { int mid = (l + r) >> 1; if (gids[mid] < g + 1) l = mid + 1; else r = mid; } hi = l; }
  float s = 0.f;
  for (int i = lo + wid; i < hi; i += 4) s += h[(size_t)i * HID + lane];
  __shared__ float red[4][64];
  __shared__ float gv[64], o1[64], o2[32];
  red[wid][lane] = s;
  __syncthreads();
  if (tid < 64) {
    float tot = red[0][tid] + red[1][tid] + red[2][tid] + red[3][tid];
    float cnt = (float)(hi - lo);
    gv[tid] = tot / fmaxf(cnt, 1.f);
  }
  __syncthreads();
  if (tid < 64) {
    float t = b1[tid];
    for (int k = 0; k < 64; ++k) t = fmaf(gv[k], W1[k * 64 + tid], t);
    o1[tid] = t > 0.f ? t : 0.01f * t;
  }
  __syncthreads();
  if (tid < 32) {
    float t = b2[tid];
    for (int k = 0; k < 64; ++k) t = fmaf(o1[k], W2[k * 32 + tid], t);
    o2[tid] = t > 0.f ? t : 0.01f * t;
  }
  __syncthreads();
  if (tid < 2) {
    float t = b3[tid];
    for (int k = 0; k < 32; ++k) t = fmaf(o2[k], W3[k * 2 + tid], t);
    out[g * 2 + tid] = t > 0.f ? t : 0.01f * t;
  }
}

// ---------------- launch ----------------

extern "C" void kernel_launch(void* const* d_in, const int* in_sizes, int n_in,
                              void* d_out, int out_size, void* d_ws, size_t ws_size,
                              hipStream_t stream) {
  const float* x    = (const float*)d_in[0];
  const int*   src  = (const int*)d_in[1];
  const int*   dst  = (const int*)d_in[2];
  const int*   gids = (const int*)d_in[3];
  const float* Wsrc1 = (const float*)d_in[5];
  const float* bsrc1 = (const float*)d_in[6];
  const float* Wdst1 = (const float*)d_in[7];
  const float* bdst1 = (const float*)d_in[8];
  const float* attn1 = (const float*)d_in[9];
  const float* Wsrc2 = (const float*)d_in[10];
  const float* bsrc2 = (const float*)d_in[11];
  const float* Wdst2 = (const float*)d_in[12];
  const float* bdst2 = (const float*)d_in[13];
  const float* attn2 = (const float*)d_in[14];
  const float* Wsrc3 = (const float*)d_in[15];
  const float* bsrc3 = (const float*)d_in[16];
  const float* Wdst3 = (const float*)d_in[17];
  const float* bdst3 = (const float*)d_in[18];
  const float* attn3 = (const float*)d_in[19];
  const float* W1 = (const float*)d_in[20];
  const float* b1 = (const float*)d_in[21];
  const float* W2 = (const float*)d_in[22];
  const float* b2 = (const float*)d_in[23];
  const float* W3 = (const float*)d_in[24];
  const float* b3 = (const float*)d_in[25];
  float* out = (float*)d_out;

  float* fsfd  = (float*)d_ws;                         // N*384 f32
  float* h     = fsfd + (size_t)N_NODES * D2;          // N*192 f32
  int* counts  = (int*)(h + (size_t)N_NODES * D1);     // N (cursor)
  int* indptr  = counts + N_NODES;                     // N+1
  int* ssrc    = indptr + (N_NODES + 1);               // E
  int* bsum    = ssrc + N_EDGES;                       // ceil(N/256)

  const int NSCAN = (N_NODES + 255) / 256;             // 196

  zero_int_kernel<<<(N_NODES + 255) / 256, 256, 0, stream>>>(counts, N_NODES);
  hist_kernel<<<(N_EDGES + 255) / 256, 256, 0, stream>>>(dst, counts, N_EDGES);
  scan_blocks_kernel<<<NSCAN, 256, 0, stream>>>(counts, indptr, bsum, N_NODES);
  scan_sums_kernel<<<1, 256, 0, stream>>>(bsum, NSCAN);
  add_offs_kernel<<<NSCAN, 256, 0, stream>>>(indptr, bsum, counts, N_NODES);
  scatter_kernel<<<(N_EDGES + 255) / 256, 256, 0, stream>>>(src, dst, counts, ssrc, N_EDGES);

  dim3 ggrid(3, (N_NODES + 127) / 128);
  dim3 egrid((N_NODES + 3) / 4);

  gemm_kernel<<<ggrid, 256, 0, stream>>>(x, N_NODES, F_INPUT, Wsrc1, bsrc1, Wdst1, bdst1, fsfd);
  edge_kernel<0><<<egrid, 256, 0, stream>>>(fsfd, indptr, ssrc, attn1, h);

  gemm_kernel<<<ggrid, 256, 0, stream>>>(h, N_NODES, D1, Wsrc2, bsrc2, Wdst2, bdst2, fsfd);
  edge_kernel<0><<<egrid, 256, 0, stream>>>(fsfd, indptr, ssrc, attn2, h);

  gemm_kernel<<<ggrid, 256, 0, stream>>>(h, N_NODES, D1, Wsrc3, bsrc3, Wdst3, bdst3, fsfd);
  edge_kernel<1><<<egrid, 256, 0, stream>>>(fsfd, indptr, ssrc, attn3, h);

  pool_mlp_kernel<<<NGRAPH, 256, 0, stream>>>(h, gids, W1, b1, W2, b2, W3, b3, out);
}

// Round 11
// 740.107 us; speedup vs baseline: 1.2075x; 1.2075x over previous
//
#include <hip/hip_runtime.h>
#include <math.h>

#define N_NODES 50000
#define N_EDGES 800000
#define F_INPUT 128
#define HID 64
#define NHEAD 3
#define NGRAPH 50
#define D1 192   // NHEAD*HID
#define D2 384   // 2*D1 (fs|fd)
#define NF 24    // 384/16 N-fragments
#define MF 3125  // 50000/16 M-fragments

typedef __attribute__((ext_vector_type(8))) short bf16x8;
typedef __attribute__((ext_vector_type(4))) short short4v;
typedef __attribute__((ext_vector_type(4))) float f32x4;

// 16-lane (DPP row) all-reduce add via row_ror rotate-add; pure VALU, no DS pipe.
#define ROR_ADD(v, C) \
  ((v) + __int_as_float(__builtin_amdgcn_update_dpp(0, __float_as_int(v), (C), 0xF, 0xF, true)))

// bf16 round-to-nearest-even via bit math
__device__ __forceinline__ unsigned short f2bf(float x) {
  unsigned u = __float_as_uint(x);
  return (unsigned short)((u + 0x7FFFu + ((u >> 16) & 1u)) >> 16);
}
__device__ __forceinline__ float bf2f(unsigned short h) {
  return __uint_as_float(((unsigned)h) << 16);
}
__device__ __forceinline__ void split3(float x, unsigned short& o1, unsigned short& o2, unsigned short& o3) {
  o1 = f2bf(x); float f1 = bf2f(o1);
  float r1 = x - f1; o2 = f2bf(r1); float f2 = bf2f(o2);
  o3 = f2bf(r1 - f2);
}

// ---------------- graph-structure kernels ----------------

__global__ void zero_int_kernel(int* __restrict__ p, int n) {
  int i = blockIdx.x * blockDim.x + threadIdx.x;
  if (i < n) p[i] = 0;
}

__global__ void hist_kernel(const int* __restrict__ dst, int* __restrict__ counts, int e) {
  int i = blockIdx.x * blockDim.x + threadIdx.x;
  if (i < e) atomicAdd(&counts[dst[i]], 1);
}

__global__ __launch_bounds__(256)
void scan_blocks_kernel(const int* __restrict__ counts, int* __restrict__ indptr,
                        int* __restrict__ bsum, int n) {
  __shared__ int wt[4];
  int tid = threadIdx.x, lane = tid & 63, wid = tid >> 6;
  int i = blockIdx.x * 256 + tid;
  int x = (i < n) ? counts[i] : 0;
  #pragma unroll
  for (int off = 1; off < 64; off <<= 1) {
    int t = __shfl_up(x, off, 64);
    if (lane >= off) x += t;
  }
  if (lane == 63) wt[wid] = x;
  __syncthreads();
  int woff = 0;
  #pragma unroll
  for (int w = 0; w < 4; ++w) if (w < wid) woff += wt[w];
  x += woff;
  if (i < n) indptr[i + 1] = x;
  if (tid == 255) bsum[blockIdx.x] = x;
}

__global__ __launch_bounds__(256)
void scan_sums_kernel(int* __restrict__ bsum, int nb) {
  __shared__ int wt[4];
  int tid = threadIdx.x, lane = tid & 63, wid = tid >> 6;
  int v = (tid < nb) ? bsum[tid] : 0;
  int x = v;
  #pragma unroll
  for (int off = 1; off < 64; off <<= 1) {
    int t = __shfl_up(x, off, 64);
    if (lane >= off) x += t;
  }
  if (lane == 63) wt[wid] = x;
  __syncthreads();
  int woff = 0;
  #pragma unroll
  for (int w = 0; w < 4; ++w) if (w < wid) woff += wt[w];
  if (tid < nb) bsum[tid] = woff + x - v;
}

__global__ void add_offs_kernel(int* __restrict__ indptr, const int* __restrict__ bsum,
                                int* __restrict__ cursor, int n) {
  int i = blockIdx.x * 256 + threadIdx.x;
  if (i == 0) { indptr[0] = 0; cursor[0] = 0; }
  if (i < n) {
    int v = indptr[i + 1] + bsum[blockIdx.x];
    indptr[i + 1] = v;
    if (i + 1 < n) cursor[i + 1] = v;
  }
}

__global__ void scatter_kernel(const int* __restrict__ src, const int* __restrict__ dst,
                               int* __restrict__ cursor, int* __restrict__ ssrc, int e) {
  int i = blockIdx.x * blockDim.x + threadIdx.x;
  if (i < e) {
    int pos = atomicAdd(&cursor[dst[i]], 1);
    ssrc[pos] = src[i];
  }
}

// ---------------- W -> fragment-ordered bf16x3 planes + fused bias ----------------
// wfrag layout: [ks][nf][pl][lane][8] ushort; frag elem j: k = ks*32+(lane>>4)*4+(j&3)+16*(j>>2),
// n = nf*16+(lane&15).  (A/B operand layout of mfma_f32_16x16x32_bf16.)

__global__ __launch_bounds__(256)
void wconv_kernel(const float* __restrict__ Wsrc, const float* __restrict__ Wdst,
                  const float* __restrict__ bsrc, const float* __restrict__ bdst,
                  int K, unsigned short* __restrict__ wfrag, float* __restrict__ biasf) {
  int t = blockIdx.x * 256 + threadIdx.x;
  if (t < D2) biasf[t] = (t < D1) ? bsrc[t] : bdst[t - D1];
  int KS = K >> 5;
  int total = KS * NF * 3 * 64;
  if (t >= total) return;
  int lane = t & 63;
  int q = t >> 6;
  int pl = q % 3; q /= 3;
  int nf = q % NF;
  int ks = q / NF;
  int n = nf * 16 + (lane & 15);
  int kg = lane >> 4;
  unsigned short out[8];
  #pragma unroll
  for (int j = 0; j < 8; ++j) {
    int k = ks * 32 + kg * 4 + (j & 3) + ((j >> 2) << 4);
    float w = (n < D1) ? Wsrc[(size_t)k * D1 + n] : Wdst[(size_t)k * D1 + (n - D1)];
    unsigned short s1, s2, s3;
    split3(w, s1, s2, s3);
    out[j] = (pl == 0) ? s1 : (pl == 1) ? s2 : s3;
  }
  *(bf16x8*)(wfrag + (size_t)t * 8) = *(bf16x8*)out;
}

// ---------------- x (f32) -> 3 bf16 planes (layer 1 only) ----------------

__global__ __launch_bounds__(256)
void aconv_kernel(const float* __restrict__ A, unsigned short* __restrict__ P,
                  int n4, size_t MK) {
  int t = blockIdx.x * 256 + threadIdx.x;
  if (t >= n4) return;
  float4 v = ((const float4*)A)[t];
  unsigned short s1[4], s2[4], s3[4];
  split3(v.x, s1[0], s2[0], s3[0]);
  split3(v.y, s1[1], s2[1], s3[1]);
  split3(v.z, s1[2], s2[2], s3[2]);
  split3(v.w, s1[3], s2[3], s3[3]);
  ((short4v*)P)[t]        = *(short4v*)s1;
  ((short4v*)(P + MK))[t] = *(short4v*)s2;
  ((short4v*)(P + 2 * MK))[t] = *(short4v*)s3;
}

// ---------------- MFMA GEMM: C[M,384] = A @ [Wsrc|Wdst] + bias, bf16x3 (6 terms) ----
// block = 4 waves, each wave one 16-row M-frag; LDS stages one K-slice of all B frags.

__global__ __launch_bounds__(256, 2)
void mfma_gemm_kernel(const unsigned short* __restrict__ Ap,
                      const unsigned short* __restrict__ Wf,
                      const float* __restrict__ biasf,
                      int K, float* __restrict__ C) {
  __shared__ unsigned short Bs[NF * 3 * 64 * 8];   // 73728 B
  const int tid = threadIdx.x;
  const int lane = tid & 63, wid = tid >> 6;
  const int mf = blockIdx.x * 4 + wid;
  const bool active = (mf < MF);
  const int rowl = lane & 15;
  const int kg = lane >> 4;
  const size_t MK = (size_t)N_NODES * K;
  const int KS = K >> 5;

  f32x4 acc[NF];
  #pragma unroll
  for (int nf = 0; nf < NF; ++nf) acc[nf] = (f32x4){0.f, 0.f, 0.f, 0.f};

  const size_t arow = (size_t)(mf * 16 + rowl) * K;

  for (int ks = 0; ks < KS; ++ks) {
    // stage this K-slice of W fragments (73728 B contiguous)
    {
      const float4* s = (const float4*)(Wf + (size_t)ks * (NF * 3 * 64 * 8));
      float4* d = (float4*)Bs;
      #pragma unroll
      for (int i = 0; i < 18; ++i) d[tid + i * 256] = s[tid + i * 256];
    }
    __syncthreads();
    if (active) {
      union { bf16x8 v; short4v h[2]; } ua1, ua2, ua3;
      const unsigned short* a0 = Ap + arow + ks * 32 + kg * 4;
      ua1.h[0] = *(const short4v*)(a0);
      ua1.h[1] = *(const short4v*)(a0 + 16);
      ua2.h[0] = *(const short4v*)(a0 + MK);
      ua2.h[1] = *(const short4v*)(a0 + MK + 16);
      ua3.h[0] = *(const short4v*)(a0 + 2 * MK);
      ua3.h[1] = *(const short4v*)(a0 + 2 * MK + 16);
      bf16x8 a1 = ua1.v, a2 = ua2.v, a3 = ua3.v;
      #pragma unroll
      for (int nf = 0; nf < NF; ++nf) {
        bf16x8 b1 = *(const bf16x8*)&Bs[(nf * 3 + 0) * 512 + lane * 8];
        bf16x8 b2 = *(const bf16x8*)&Bs[(nf * 3 + 1) * 512 + lane * 8];
        bf16x8 b3 = *(const bf16x8*)&Bs[(nf * 3 + 2) * 512 + lane * 8];
        acc[nf] = __builtin_amdgcn_mfma_f32_16x16x32_bf16(a1, b1, acc[nf], 0, 0, 0);
        acc[nf] = __builtin_amdgcn_mfma_f32_16x16x32_bf16(a1, b2, acc[nf], 0, 0, 0);
        acc[nf] = __builtin_amdgcn_mfma_f32_16x16x32_bf16(a2, b1, acc[nf], 0, 0, 0);
        acc[nf] = __builtin_amdgcn_mfma_f32_16x16x32_bf16(a1, b3, acc[nf], 0, 0, 0);
        acc[nf] = __builtin_amdgcn_mfma_f32_16x16x32_bf16(a2, b2, acc[nf], 0, 0, 0);
        acc[nf] = __builtin_amdgcn_mfma_f32_16x16x32_bf16(a3, b1, acc[nf], 0, 0, 0);
      }
    }
    __syncthreads();
  }

  if (active) {
    const int rowb = mf * 16 + kg * 4;
    #pragma unroll
    for (int nf = 0; nf < NF; ++nf) {
      int col = nf * 16 + rowl;
      float bb = biasf[col];
      float* cp = C + (size_t)rowb * D2 + col;
      cp[0]        = acc[nf][0] + bb;
      cp[D2]       = acc[nf][1] + bb;
      cp[2 * D2]   = acc[nf][2] + bb;
      cp[3 * D2]   = acc[nf][3] + bb;
    }
  }
}

// ---------------- edge phase: 1 node/wave, 4 groups x 16 lanes, lane owns 12 dims ----
// LAST=0: writes next layer's A as 3 bf16 planes; LAST=1: writes f32 h (head-mean).

template <int LAST>
__global__ __launch_bounds__(256)
void edge_kernel(const float* __restrict__ fsfd, const int* __restrict__ indptr,
                 const int* __restrict__ ssrc, const float* __restrict__ attn,
                 void* __restrict__ outv) {
  int wave = (blockIdx.x * blockDim.x + threadIdx.x) >> 6;
  if (wave >= N_NODES) return;
  int lane = threadIdx.x & 63;
  int grp = lane >> 4;
  int l16 = lane & 15;
  int db = l16 * 4;
  const int node = wave;
  const float LOG2E = 1.4426950408889634f;

  float fd[12], a[12];
  {
    const float* fdp = fsfd + (size_t)node * D2 + D1;
    *(float4*)&fd[0] = *(const float4*)(fdp + db);
    *(float4*)&fd[4] = *(const float4*)(fdp + 64 + db);
    *(float4*)&fd[8] = *(const float4*)(fdp + 128 + db);
    float4 a0 = *(const float4*)(attn + db);
    float4 a1 = *(const float4*)(attn + 64 + db);
    float4 a2 = *(const float4*)(attn + 128 + db);
    a[0]=a0.x*LOG2E; a[1]=a0.y*LOG2E; a[2]=a0.z*LOG2E; a[3]=a0.w*LOG2E;
    a[4]=a1.x*LOG2E; a[5]=a1.y*LOG2E; a[6]=a1.z*LOG2E; a[7]=a1.w*LOG2E;
    a[8]=a2.x*LOG2E; a[9]=a2.y*LOG2E; a[10]=a2.z*LOG2E; a[11]=a2.w*LOG2E;
  }
  int beg = indptr[node], end = indptr[node + 1];
  int deg = end - beg;
  int nit = (deg + 3) >> 2;

  float m[3] = {-INFINITY, -INFINITY, -INFINITY};
  float d[3] = {0.f, 0.f, 0.f};
  float c[12] = {0,0,0,0,0,0,0,0,0,0,0,0};
  float f[12] = {0,0,0,0,0,0,0,0,0,0,0,0};
  float g[12] = {0,0,0,0,0,0,0,0,0,0,0,0};

  int e0 = beg + grp;
  if (e0 < end) {
    int s = ssrc[e0];
    const float* p = fsfd + (size_t)s * D2;
    *(float4*)&f[0] = *(const float4*)(p + db);
    *(float4*)&f[4] = *(const float4*)(p + 64 + db);
    *(float4*)&f[8] = *(const float4*)(p + 128 + db);
  }
  int sNext = 0;
  { int e1 = e0 + 4; if (e1 < end) sNext = ssrc[e1]; }

  for (int it = 0; it < nit; ++it) {
    int eC = e0 + it * 4;
    int eN = eC + 4;
    int sNN = 0;
    { int e2 = eC + 8; if (e2 < end) sNN = ssrc[e2]; }
    if (eN < end) {
      const float* p = fsfd + (size_t)sNext * D2;
      *(float4*)&g[0] = *(const float4*)(p + db);
      *(float4*)&g[4] = *(const float4*)(p + 64 + db);
      *(float4*)&g[8] = *(const float4*)(p + 128 + db);
    }
    float ph0 = 0.f, ph1 = 0.f, ph2 = 0.f;
    #pragma unroll
    for (int i = 0; i < 4; ++i) {
      float t = f[i] + fd[i]; t = fmaxf(t, 0.2f * t); ph0 = fmaf(t, a[i], ph0);
    }
    #pragma unroll
    for (int i = 4; i < 8; ++i) {
      float t = f[i] + fd[i]; t = fmaxf(t, 0.2f * t); ph1 = fmaf(t, a[i], ph1);
    }
    #pragma unroll
    for (int i = 8; i < 12; ++i) {
      float t = f[i] + fd[i]; t = fmaxf(t, 0.2f * t); ph2 = fmaf(t, a[i], ph2);
    }
    ph0 = ROR_ADD(ph0, 0x128); ph1 = ROR_ADD(ph1, 0x128); ph2 = ROR_ADD(ph2, 0x128);
    ph0 = ROR_ADD(ph0, 0x124); ph1 = ROR_ADD(ph1, 0x124); ph2 = ROR_ADD(ph2, 0x124);
    ph0 = ROR_ADD(ph0, 0x122); ph1 = ROR_ADD(ph1, 0x122); ph2 = ROR_ADD(ph2, 0x122);
    ph0 = ROR_ADD(ph0, 0x121); ph1 = ROR_ADD(ph1, 0x121); ph2 = ROR_ADD(ph2, 0x121);
    if (eC < end) {
      {
        float nm = fmaxf(m[0], ph0);
        float ex = exp2f(-fabsf(ph0 - m[0]));
        float sc = (ph0 > m[0]) ? ex : 1.f;
        float p  = (ph0 > m[0]) ? 1.f : ex;
        d[0] = d[0] * sc + p; m[0] = nm;
        #pragma unroll
        for (int j = 0; j < 4; ++j) c[j] = fmaf(p, f[j], c[j] * sc);
      }
      {
        float nm = fmaxf(m[1], ph1);
        float ex = exp2f(-fabsf(ph1 - m[1]));
        float sc = (ph1 > m[1]) ? ex : 1.f;
        float p  = (ph1 > m[1]) ? 1.f : ex;
        d[1] = d[1] * sc + p; m[1] = nm;
        #pragma unroll
        for (int j = 0; j < 4; ++j) c[4 + j] = fmaf(p, f[4 + j], c[4 + j] * sc);
      }
      {
        float nm = fmaxf(m[2], ph2);
        float ex = exp2f(-fabsf(ph2 - m[2]));
        float sc = (ph2 > m[2]) ? ex : 1.f;
        float p  = (ph2 > m[2]) ? 1.f : ex;
        d[2] = d[2] * sc + p; m[2] = nm;
        #pragma unroll
        for (int j = 0; j < 4; ++j) c[8 + j] = fmaf(p, f[8 + j], c[8 + j] * sc);
      }
    }
    #pragma unroll
    for (int i = 0; i < 12; ++i) f[i] = g[i];
    sNext = sNN;
  }

  float M0 = m[0], M1 = m[1], M2 = m[2];
  #pragma unroll
  for (int off = 16; off < 64; off <<= 1) {
    M0 = fmaxf(M0, __shfl_xor(M0, off, 64));
    M1 = fmaxf(M1, __shfl_xor(M1, off, 64));
    M2 = fmaxf(M2, __shfl_xor(M2, off, 64));
  }
  float s0 = (m[0] == M0) ? 1.f : exp2f(m[0] - M0);
  float s1 = (m[1] == M1) ? 1.f : exp2f(m[1] - M1);
  float s2f = (m[2] == M2) ? 1.f : exp2f(m[2] - M2);
  d[0] *= s0; d[1] *= s1; d[2] *= s2f;
  #pragma unroll
  for (int j = 0; j < 4; ++j) { c[j] *= s0; c[4 + j] *= s1; c[8 + j] *= s2f; }
  #pragma unroll
  for (int off = 16; off < 64; off <<= 1) {
    d[0] += __shfl_xor(d[0], off, 64);
    d[1] += __shfl_xor(d[1], off, 64);
    d[2] += __shfl_xor(d[2], off, 64);
    #pragma unroll
    for (int i = 0; i < 12; ++i) c[i] += __shfl_xor(c[i], off, 64);
  }
  float r[12];
  float i0 = d[0] > 0.f ? 1.f / d[0] : 0.f;
  float i1 = d[1] > 0.f ? 1.f / d[1] : 0.f;
  float i2 = d[2] > 0.f ? 1.f / d[2] : 0.f;
  #pragma unroll
  for (int j = 0; j < 4; ++j) { r[j] = c[j] * i0; r[4 + j] = c[4 + j] * i1; r[8 + j] = c[8 + j] * i2; }

  if (grp == 0) {
    if (LAST) {
      float* out = (float*)outv;
      float4 o;
      o.x = (r[0] + r[4] + r[8])  * (1.f / 3.f);
      o.y = (r[1] + r[5] + r[9])  * (1.f / 3.f);
      o.z = (r[2] + r[6] + r[10]) * (1.f / 3.f);
      o.w = (r[3] + r[7] + r[11]) * (1.f / 3.f);
      *(float4*)(out + (size_t)node * HID + db) = o;
    } else {
      // write 3 bf16 planes of next layer's A ([M][192] each)
      unsigned short* P = (unsigned short*)outv;
      const size_t MK2 = (size_t)N_NODES * D1;
      unsigned short s1[12], s2[12], s3[12];
      #pragma unroll
      for (int i = 0; i < 12; ++i) split3(r[i], s1[i], s2[i], s3[i]);
      #pragma unroll
      for (int hh = 0; hh < 3; ++hh) {
        size_t base = (size_t)node * D1 + hh * 64 + db;
        *(short4v*)(P + base)           = *(short4v*)&s1[hh * 4];
        *(short4v*)(P + MK2 + base)     = *(short4v*)&s2[hh * 4];
        *(short4v*)(P + 2 * MK2 + base) = *(short4v*)&s3[hh * 4];
      }
    }
  }
}

// ---------------- per-graph mean pool + 3-layer MLP ----------------

__global__ __launch_bounds__(256)
void pool_mlp_kernel(const float* __restrict__ h, const int* __restrict__ gids,
                     const float* __restrict__ W1, const float* __restrict__ b1,
                     const float* __restrict__ W2, const float* __restrict__ b2,
                     const float* __restrict__ W3, const float* __restrict__ b3,
                     float* __restrict__ out) {
  int g = blockIdx.x;
  int tid = threadIdx.x;
  int lane = tid & 63, wid = tid >> 6;
  int lo, hi;
  { int l = 0, r = N_NODES; while (l < r) { int mid = (l + r) >> 1; if (gids[mid] < g) l = mid + 1; else r = mid; } lo = l; }
  { int l = 0, r = N_NODES; while (l < r) { int mid = (l + r) >> 1; if (gids[mid] < g + 1) l = mid + 1; else r = mid; } hi = l; }
  float s = 0.f;
  for (int i = lo + wid; i < hi; i += 4) s += h[(size_t)i * HID + lane];
  __shared__ float red[4][64];
  __shared__ float gv[64], o1[64], o2[32];
  red[wid][lane] = s;
  __syncthreads();
  if (tid < 64) {
    float tot = red[0][tid] + red[1][tid] + red[2][tid] + red[3][tid];
    float cnt = (float)(hi - lo);
    gv[tid] = tot / fmaxf(cnt, 1.f);
  }
  __syncthreads();
  if (tid < 64) {
    float t = b1[tid];
    for (int k = 0; k < 64; ++k) t = fmaf(gv[k], W1[k * 64 + tid], t);
    o1[tid] = t > 0.f ? t : 0.01f * t;
  }
  __syncthreads();
  if (tid < 32) {
    float t = b2[tid];
    for (int k = 0; k < 64; ++k) t = fmaf(o1[k], W2[k * 32 + tid], t);
    o2[tid] = t > 0.f ? t : 0.01f * t;
  }
  __syncthreads();
  if (tid < 2) {
    float t = b3[tid];
    for (int k = 0; k < 32; ++k) t = fmaf(o2[k], W3[k * 2 + tid], t);
    out[g * 2 + tid] = t > 0.f ? t : 0.01f * t;
  }
}

// ---------------- launch ----------------

extern "C" void kernel_launch(void* const* d_in, const int* in_sizes, int n_in,
                              void* d_out, int out_size, void* d_ws, size_t ws_size,
                              hipStream_t stream) {
  const float* x    = (const float*)d_in[0];
  const int*   src  = (const int*)d_in[1];
  const int*   dst  = (const int*)d_in[2];
  const int*   gids = (const int*)d_in[3];
  const float* Wsrc1 = (const float*)d_in[5];
  const float* bsrc1 = (const float*)d_in[6];
  const float* Wdst1 = (const float*)d_in[7];
  const float* bdst1 = (const float*)d_in[8];
  const float* attn1 = (const float*)d_in[9];
  const float* Wsrc2 = (const float*)d_in[10];
  const float* bsrc2 = (const float*)d_in[11];
  const float* Wdst2 = (const float*)d_in[12];
  const float* bdst2 = (const float*)d_in[13];
  const float* attn2 = (const float*)d_in[14];
  const float* Wsrc3 = (const float*)d_in[15];
  const float* bsrc3 = (const float*)d_in[16];
  const float* Wdst3 = (const float*)d_in[17];
  const float* bdst3 = (const float*)d_in[18];
  const float* attn3 = (const float*)d_in[19];
  const float* W1 = (const float*)d_in[20];
  const float* b1 = (const float*)d_in[21];
  const float* W2 = (const float*)d_in[22];
  const float* b2 = (const float*)d_in[23];
  const float* W3 = (const float*)d_in[24];
  const float* b3 = (const float*)d_in[25];
  float* out = (float*)d_out;

  // workspace (~139 MB)
  float* fsfd = (float*)d_ws;                                  // M*384 f32
  unsigned short* planes = (unsigned short*)(fsfd + (size_t)N_NODES * D2);  // 3*M*192 bf16
  unsigned short* wfrag = planes + (size_t)3 * N_NODES * D1;   // 27648*8 ushort
  float* biasf = (float*)(wfrag + 27648 * 8);                  // 384 f32
  int* counts  = (int*)(biasf + 384);                          // N
  int* indptr  = counts + N_NODES;                             // N+1
  int* ssrc    = indptr + (N_NODES + 1);                       // E
  int* bsum    = ssrc + N_EDGES;                               // ceil(N/256)
  float* hlast = (float*)planes;                               // alias: M*64 f32 (after gemm3)

  const int NSCAN = (N_NODES + 255) / 256;

  zero_int_kernel<<<(N_NODES + 255) / 256, 256, 0, stream>>>(counts, N_NODES);
  hist_kernel<<<(N_EDGES + 255) / 256, 256, 0, stream>>>(dst, counts, N_EDGES);
  scan_blocks_kernel<<<NSCAN, 256, 0, stream>>>(counts, indptr, bsum, N_NODES);
  scan_sums_kernel<<<1, 256, 0, stream>>>(bsum, NSCAN);
  add_offs_kernel<<<NSCAN, 256, 0, stream>>>(indptr, bsum, counts, N_NODES);
  scatter_kernel<<<(N_EDGES + 255) / 256, 256, 0, stream>>>(src, dst, counts, ssrc, N_EDGES);

  dim3 egrid((N_NODES + 3) / 4);
  const int GG = (MF + 3) / 4;   // 782 blocks for mfma_gemm

  // layer 1 (K=128)
  wconv_kernel<<<108, 256, 0, stream>>>(Wsrc1, Wdst1, bsrc1, bdst1, F_INPUT, wfrag, biasf);
  aconv_kernel<<<(N_NODES * F_INPUT / 4 + 255) / 256, 256, 0, stream>>>(
      x, planes, N_NODES * F_INPUT / 4, (size_t)N_NODES * F_INPUT);
  mfma_gemm_kernel<<<GG, 256, 0, stream>>>(planes, wfrag, biasf, F_INPUT, fsfd);
  edge_kernel<0><<<egrid, 256, 0, stream>>>(fsfd, indptr, ssrc, attn1, planes);

  // layer 2 (K=192)
  wconv_kernel<<<108, 256, 0, stream>>>(Wsrc2, Wdst2, bsrc2, bdst2, D1, wfrag, biasf);
  mfma_gemm_kernel<<<GG, 256, 0, stream>>>(planes, wfrag, biasf, D1, fsfd);
  edge_kernel<0><<<egrid, 256, 0, stream>>>(fsfd, indptr, ssrc, attn2, planes);

  // layer 3 (K=192)
  wconv_kernel<<<108, 256, 0, stream>>>(Wsrc3, Wdst3, bsrc3, bdst3, D1, wfrag, biasf);
  mfma_gemm_kernel<<<GG, 256, 0, stream>>>(planes, wfrag, biasf, D1, fsfd);
  edge_kernel<1><<<egrid, 256, 0, stream>>>(fsfd, indptr, ssrc, attn3, hlast);

  pool_mlp_kernel<<<NGRAPH, 256, 0, stream>>>(hlast, gids, W1, b1, W2, b2, W3, b3, out);
}